// Round 4
// baseline (19.177 us; speedup 1.0000x reference)
//
#include <hip/hip_runtime.h>
#include <math.h>

#define N_IN   128
#define N_OUT  128
#define BATCH  512
#define NB     11
#define FJ     12
#define BM     32                  // batch rows per block
#define NO     32                  // outputs per block
#define IC     16                  // input features per K-chunk
#define NCHUNK (N_IN / IC)         // 8
#define LSTR   200                 // LDS row stride (bf16): 192 data + 8 pad (400 B)

typedef __attribute__((ext_vector_type(8))) short bf16x8;
typedef __attribute__((ext_vector_type(4))) float f32x4;

static __device__ __forceinline__ unsigned short f2bf(float f) {
    union { float f; unsigned u; } v; v.f = f;
    unsigned r = v.u + 0x7FFF + ((v.u >> 16) & 1);   // RNE
    return (unsigned short)(r >> 16);
}

// Fully fused KAN layer: out = F(x) · W^T, built on the fly per K-chunk in LDS.
// F[b][i*12+j] = basis_j(x[b,i]) (j<11), silu(x[b,i]) (j=11)
// W[o][i*12+j] = c_spl[o,i]*c_basis[o*128+i][j] (j<11), c_res[o,i] (j=11)
__global__ __launch_bounds__(512) void kan_one(
    const float* __restrict__ x, const float* __restrict__ grid,
    const float* __restrict__ c_basis, const float* __restrict__ c_res,
    const float* __restrict__ c_spl, float* __restrict__ out)
{
    __shared__ unsigned short Wl[NO * LSTR];   // 12.8 KB
    __shared__ unsigned short Fl[BM * LSTR];   // 12.8 KB
    __shared__ float part[8][256];             // 8 KB
    const int t  = threadIdx.x;
    const int b0 = blockIdx.x * BM;
    const int o0 = blockIdx.y * NO;
    const int il = t & 15;                     // feature within chunk
    const int rl = t >> 4;                     // 0..31: o-local (W) / b-local (F)
    const float lo = grid[3];
    const float hr = 1.0f / (grid[4] - grid[3]);

    // ---- prefetch chunk 0 operands into regs ----
    float cb[NB], spl, res, xv;
    {
        const int e = (o0 + rl) * N_IN + il;
        #pragma unroll
        for (int j = 0; j < NB; ++j) cb[j] = c_basis[e * NB + j];
        spl = c_spl[e];  res = c_res[e];
        xv  = x[(b0 + rl) * N_IN + il];
    }

    const int wv   = t >> 6;         // wave 0..7 = kh*4 + mt*2 + nt
    const int lane = t & 63;
    const int kh   = wv >> 2;        // K half
    const int mt   = (wv >> 1) & 1;  // m-tile
    const int nt   = wv & 1;         // n-tile
    f32x4 acc = {0.f, 0.f, 0.f, 0.f};

    for (int ch = 0; ch < NCHUNK; ++ch) {
        // ---- VALU: build packed bf16 rows from regs ----
        unsigned int wpk[6], fpk[6];
        {
            float wv12[12];
            #pragma unroll
            for (int j = 0; j < NB; ++j) wv12[j] = spl * cb[j];
            wv12[11] = res;
            #pragma unroll
            for (int j = 0; j < 6; ++j)
                wpk[j] = (unsigned)f2bf(wv12[2*j]) | ((unsigned)f2bf(wv12[2*j+1]) << 16);

            const float s = (xv - lo) * hr;            // in [0,8)
            int c = (int)s; c = c < 0 ? 0 : (c > 7 ? 7 : c);
            const float u  = s - (float)c;
            const float um = 1.0f - u;
            const float u2 = u * u, u3 = u2 * u;
            const float B0 = um * um * um * (1.0f / 6.0f);
            const float B1 = (3.0f * u3 - 6.0f * u2 + 4.0f) * (1.0f / 6.0f);
            const float B2 = (-3.0f * u3 + 3.0f * u2 + 3.0f * u + 1.0f) * (1.0f / 6.0f);
            const float B3 = u3 * (1.0f / 6.0f);
            float fv12[12];
            #pragma unroll
            for (int j = 0; j < NB; ++j) {
                const int r = j - c;
                fv12[j] = (r == 0) ? B0 : (r == 1) ? B1 : (r == 2) ? B2 : (r == 3) ? B3 : 0.0f;
            }
            fv12[11] = xv / (1.0f + __expf(-xv));      // silu
            #pragma unroll
            for (int j = 0; j < 6; ++j)
                fpk[j] = (unsigned)f2bf(fv12[2*j]) | ((unsigned)f2bf(fv12[2*j+1]) << 16);
        }

        __syncthreads();   // all waves done reading previous chunk's LDS
        {
            unsigned int* wd = (unsigned int*)&Wl[rl * LSTR + il * FJ];
            unsigned int* fd = (unsigned int*)&Fl[rl * LSTR + il * FJ];
            #pragma unroll
            for (int j = 0; j < 6; ++j) { wd[j] = wpk[j]; fd[j] = fpk[j]; }
        }
        __syncthreads();   // chunk ready

        // ---- issue-early: prefetch chunk ch+1 (latency hides under MFMA) ----
        if (ch + 1 < NCHUNK) {
            const int i = (ch + 1) * IC + il;
            const int e = (o0 + rl) * N_IN + i;
            #pragma unroll
            for (int j = 0; j < NB; ++j) cb[j] = c_basis[e * NB + j];
            spl = c_spl[e];  res = c_res[e];
            xv  = x[(b0 + rl) * N_IN + i];
        }

        // ---- MFMA: tile (mt,nt), K-half kh -> 3 steps of K=32 ----
        const int kb = kh * 3;
        #pragma unroll
        for (int ks = 0; ks < 3; ++ks) {
            const int k = (kb + ks) * 32 + (lane >> 4) * 8;
            const bf16x8 a = *(const bf16x8*)&Fl[(mt * 16 + (lane & 15)) * LSTR + k];
            const bf16x8 b = *(const bf16x8*)&Wl[(nt * 16 + (lane & 15)) * LSTR + k];
            acc = __builtin_amdgcn_mfma_f32_16x16x32_bf16(a, b, acc, 0, 0, 0);
        }
    }

    // ---- cross-wave K reduce + store ----
    #pragma unroll
    for (int r = 0; r < 4; ++r)
        part[wv][((lane >> 4) * 4 + r) * 16 + (lane & 15)] = acc[r];
    __syncthreads();

    #pragma unroll
    for (int q = 0; q < 2; ++q) {
        const int slot = q * 512 + t;          // 4 tiles x 256 slots
        const int tile = slot >> 8;            // mt*2 + nt
        const int s    = slot & 255;
        const int row  = s >> 4, col = s & 15;
        const float v  = part[tile][s] + part[tile + 4][s];
        out[(b0 + (tile >> 1) * 16 + row) * N_OUT + o0 + (tile & 1) * 16 + col] = v;
    }
}

extern "C" void kernel_launch(void* const* d_in, const int* in_sizes, int n_in,
                              void* d_out, int out_size, void* d_ws, size_t ws_size,
                              hipStream_t stream) {
    const float* x       = (const float*)d_in[0];
    const float* grid    = (const float*)d_in[1];
    const float* c_basis = (const float*)d_in[2];
    const float* c_res   = (const float*)d_in[3];
    const float* c_spl   = (const float*)d_in[4];
    float* out = (float*)d_out;

    dim3 g(BATCH / BM, N_OUT / NO);            // 16 x 4 = 64 blocks, 512 thr
    kan_one<<<g, 512, 0, stream>>>(x, grid, c_basis, c_res, c_spl, out);
}

// Round 5
// 12.865 us; speedup vs baseline: 1.4907x; 1.4907x over previous
//
#include <hip/hip_runtime.h>
#include <math.h>

#define N_IN   128
#define N_OUT  128
#define BATCH  512
#define NB     11
#define FJ     12
#define KD     (N_IN * FJ)         // 1536
#define LSTR   1544                // row stride in bf16: 3088 B == 4 words mod 32 banks

typedef __attribute__((ext_vector_type(8))) short bf16x8;
typedef __attribute__((ext_vector_type(4))) float f32x4;

static __device__ __forceinline__ unsigned short f2bf(float f) {
    union { float f; unsigned u; } v; v.f = f;
    unsigned r = v.u + 0x7FFF + ((v.u >> 16) & 1);   // RNE
    return (unsigned short)(r >> 16);
}

// One fused kernel: block = 16x16 output tile, 512 threads (8 waves).
// Phase 1: build F[16][1536] (basis+silu of x-rows) and W[16][1536]
// (c_spl*c_basis ‖ c_res) in LDS as bf16.  Phase 2: 8-way K-split MFMA.
__global__ __launch_bounds__(512) void kan_fused1(
    const float* __restrict__ x, const float* __restrict__ grid,
    const float* __restrict__ c_basis, const float* __restrict__ c_res,
    const float* __restrict__ c_spl, float* __restrict__ out)
{
    __shared__ unsigned short Fl[16 * LSTR];   // 49.4 KB
    __shared__ unsigned short Wl[16 * LSTR];   // 49.4 KB
    __shared__ float part[8][256];             // 8 KB
    const int t  = threadIdx.x;
    const int m0 = blockIdx.x * 16;            // batch rows
    const int n0 = blockIdx.y * 16;            // output cols
    const float lo = grid[3];
    const float hr = 1.0f / (grid[4] - grid[3]);

    // ---- Phase 1a: 2048 F-evals, 4 per thread (branch-free) ----
    #pragma unroll
    for (int r = 0; r < 4; ++r) {
        const int p  = t + r * 512;            // 0..2047
        const int bl = p >> 7;                 // local batch row
        const int i  = p & 127;                // input feature
        const float xv = x[(m0 + bl) * N_IN + i];
        const float s  = (xv - lo) * hr;       // in [0,8)
        int c = (int)s; c = c < 0 ? 0 : (c > 7 ? 7 : c);
        const float u  = s - (float)c;
        const float um = 1.0f - u;
        const float u2 = u * u, u3 = u2 * u;
        const float B0 = um * um * um * (1.0f / 6.0f);
        const float B1 = (3.0f * u3 - 6.0f * u2 + 4.0f) * (1.0f / 6.0f);
        const float B2 = (-3.0f * u3 + 3.0f * u2 + 3.0f * u + 1.0f) * (1.0f / 6.0f);
        const float B3 = u3 * (1.0f / 6.0f);
        float fv[12];
        #pragma unroll
        for (int j = 0; j < NB; ++j) {
            const int d = j - c;
            fv[j] = (d == 0) ? B0 : (d == 1) ? B1 : (d == 2) ? B2 : (d == 3) ? B3 : 0.0f;
        }
        fv[11] = xv / (1.0f + __expf(-xv));    // silu
        unsigned int* dst = (unsigned int*)&Fl[bl * LSTR + i * FJ];
        #pragma unroll
        for (int j = 0; j < 6; ++j)
            dst[j] = (unsigned)f2bf(fv[2*j]) | ((unsigned)f2bf(fv[2*j+1]) << 16);
    }

    // ---- Phase 1b: 2048 W-rows, 4 per thread ----
    #pragma unroll
    for (int r = 0; r < 4; ++r) {
        const int p  = t + r * 512;            // 0..2047
        const int ol = p >> 7;                 // local output
        const int i  = p & 127;
        const int e  = (n0 + ol) * N_IN + i;
        const float sp = c_spl[e];
        float wvv[12];
        #pragma unroll
        for (int j = 0; j < NB; ++j) wvv[j] = sp * c_basis[e * NB + j];
        wvv[11] = c_res[e];
        unsigned int* dst = (unsigned int*)&Wl[ol * LSTR + i * FJ];
        #pragma unroll
        for (int j = 0; j < 6; ++j)
            dst[j] = (unsigned)f2bf(wvv[2*j]) | ((unsigned)f2bf(wvv[2*j+1]) << 16);
    }

    __syncthreads();

    // ---- Phase 2: 8 waves split K=1536 into 8x192 -> 6 MFMA each ----
    const int wv   = t >> 6;
    const int lane = t & 63;
    const int row  = lane & 15;
    const int kq   = (lane >> 4) * 8;
    const int k0   = wv * (KD / 8);            // 192
    f32x4 acc = {0.f, 0.f, 0.f, 0.f};
    #pragma unroll
    for (int ks = 0; ks < 6; ++ks) {
        const int k = k0 + ks * 32 + kq;
        const bf16x8 a = *(const bf16x8*)&Fl[row * LSTR + k];
        const bf16x8 b = *(const bf16x8*)&Wl[row * LSTR + k];
        acc = __builtin_amdgcn_mfma_f32_16x16x32_bf16(a, b, acc, 0, 0, 0);
    }

    // C/D layout (m89): col = lane&15, row = (lane>>4)*4 + r
    #pragma unroll
    for (int r = 0; r < 4; ++r)
        part[wv][((lane >> 4) * 4 + r) * 16 + (lane & 15)] = acc[r];
    __syncthreads();

    if (t < 256) {
        float s = part[0][t] + part[1][t] + part[2][t] + part[3][t]
                + part[4][t] + part[5][t] + part[6][t] + part[7][t];
        out[(m0 + (t >> 4)) * N_OUT + n0 + (t & 15)] = s;
    }
}

extern "C" void kernel_launch(void* const* d_in, const int* in_sizes, int n_in,
                              void* d_out, int out_size, void* d_ws, size_t ws_size,
                              hipStream_t stream) {
    const float* x       = (const float*)d_in[0];
    const float* grid    = (const float*)d_in[1];
    const float* c_basis = (const float*)d_in[2];
    const float* c_res   = (const float*)d_in[3];
    const float* c_spl   = (const float*)d_in[4];
    float* out = (float*)d_out;

    dim3 g(BATCH / 16, N_OUT / 16);            // 32 x 8 = 256 blocks, 1/CU
    kan_fused1<<<g, 512, 0, stream>>>(x, grid, c_basis, c_res, c_spl, out);
}